// Round 1
// baseline (340.411 us; speedup 1.0000x reference)
//
#include <hip/hip_runtime.h>
#include <hip/hip_bf16.h>
#include <cstddef>

// ---------------------------------------------------------------------------
// GAT 2-layer forward. N=50000 nodes, E=800000 edges (+N self loops).
// Pipeline per call:
//   CSR build (deg hist -> scan -> fill)  [graph shared by both layers]
//   L1: gemm_alpha<128> -> aggregate<RELU=true>  (writes to d_out as scratch)
//   L2: gemm_alpha<64>  -> aggregate<RELU=false> (writes final d_out)
// ---------------------------------------------------------------------------

#define NNODES 50000
#define NEDGES 800000
#define NETOT  850000
#define FOUT   64

// ---------------- CSR build ----------------

__global__ void k_init_deg(int* __restrict__ deg, int n) {
    int i = blockIdx.x * 256 + threadIdx.x;
    if (i < n) deg[i] = 1;   // self loop
}

__global__ void k_hist(const int* __restrict__ dst, int* __restrict__ deg, int E) {
    int i = blockIdx.x * 256 + threadIdx.x;
    if (i < E) atomicAdd(&deg[dst[i]], 1);
}

__global__ void k_scan1(const int* __restrict__ deg, int* __restrict__ bsum, int n) {
    int t = threadIdx.x;
    int g = blockIdx.x * 256 + t;
    int v = (g < n) ? deg[g] : 0;
    #pragma unroll
    for (int d = 1; d < 64; d <<= 1) v += __shfl_xor(v, d);
    __shared__ int ws[4];
    if ((t & 63) == 0) ws[t >> 6] = v;
    __syncthreads();
    if (t == 0) bsum[blockIdx.x] = ws[0] + ws[1] + ws[2] + ws[3];
}

__global__ void k_scan2(const int* __restrict__ bsum, int* __restrict__ boff, int nb) {
    int t = threadIdx.x, lane = t & 63, wv = t >> 6;
    int v = (t < nb) ? bsum[t] : 0;
    int inc = v;
    #pragma unroll
    for (int d = 1; d < 64; d <<= 1) { int u = __shfl_up(inc, d); if (lane >= d) inc += u; }
    __shared__ int wsum[4];
    if (lane == 63) wsum[wv] = inc;
    __syncthreads();
    int woff = 0;
    for (int w = 0; w < wv; ++w) woff += wsum[w];
    if (t < nb) boff[t] = woff + inc - v;
}

__global__ void k_scan3(const int* __restrict__ deg, const int* __restrict__ boff,
                        int* __restrict__ rowptr, int* __restrict__ cursor, int n) {
    int t = threadIdx.x, lane = t & 63, wv = t >> 6;
    int g = blockIdx.x * 256 + t;
    int v = (g < n) ? deg[g] : 0;
    int inc = v;
    #pragma unroll
    for (int d = 1; d < 64; d <<= 1) { int u = __shfl_up(inc, d); if (lane >= d) inc += u; }
    __shared__ int wsum[4];
    if (lane == 63) wsum[wv] = inc;
    __syncthreads();
    int woff = 0;
    for (int w = 0; w < wv; ++w) woff += wsum[w];
    int excl = boff[blockIdx.x] + woff + (inc - v);
    if (g < n) {
        rowptr[g] = excl;
        cursor[g] = excl;
        if (g == n - 1) rowptr[n] = excl + v;
    }
}

__global__ void k_fill(const int* __restrict__ ei, int* __restrict__ cursor,
                       int* __restrict__ csrc, int E, int n) {
    int i = blockIdx.x * 256 + threadIdx.x;
    if (i < E) {
        int s = ei[i];
        int d = ei[E + i];
        int slot = atomicAdd(&cursor[d], 1);
        csrc[slot] = s;
    } else if (i < E + n) {
        int node = i - E;
        int slot = atomicAdd(&cursor[node], 1);
        csrc[slot] = node;
    }
}

// ---------------- GEMM + alpha (h = x@W, as = h@a_src, ad = h@a_dst) -------
// Block: 64 rows x 64 cols. 4 waves; wave w covers cols [w*16, w*16+16).
// Lane (rg = lane&15, cg = lane>>4): rows rg*4..rg*4+3, cols c0..c0+3.

template <int K>
__global__ __launch_bounds__(256) void gemm_alpha(
    const float* __restrict__ x, const float* __restrict__ W,
    const float* __restrict__ a_src, const float* __restrict__ a_dst,
    float* __restrict__ h, float* __restrict__ as_, float* __restrict__ ad_, int n)
{
    __shared__ __align__(16) float Ws[K * 64];   // Ws[k*64 + c]
    __shared__ __align__(16) float xT[K * 64];   // xT[k*64 + r]
    __shared__ float red_s[4][64];
    __shared__ float red_d[4][64];

    const int t = threadIdx.x;
    const int lane = t & 63;
    const int wv = t >> 6;
    const int rg = lane & 15;
    const int cg = lane >> 4;
    const int r0 = blockIdx.x * 64;
    const int c0 = wv * 16 + cg * 4;

    // stage W (same layout as global, coalesced, conflict-free)
    {
        const float4* Wg = (const float4*)W;
        float4* Wl = (float4*)Ws;
        for (int i = t; i < K * 16; i += 256) Wl[i] = Wg[i];
    }
    // stage x transposed: lane reads 16B of its row (cache-friendly across kq),
    // LDS writes are stride-1 across lanes -> conflict-free.
    for (int i = t; i < 16 * K; i += 256) {
        int r = i & 63;
        int kq = i >> 6;
        int row = r0 + r;
        float4 v = make_float4(0.f, 0.f, 0.f, 0.f);
        if (row < n) v = ((const float4*)(x + (size_t)row * K))[kq];
        xT[(kq * 4 + 0) * 64 + r] = v.x;
        xT[(kq * 4 + 1) * 64 + r] = v.y;
        xT[(kq * 4 + 2) * 64 + r] = v.z;
        xT[(kq * 4 + 3) * 64 + r] = v.w;
    }
    __syncthreads();

    float acc[4][4];
    #pragma unroll
    for (int i = 0; i < 4; ++i)
        #pragma unroll
        for (int j = 0; j < 4; ++j) acc[i][j] = 0.f;

    #pragma unroll 4
    for (int k = 0; k < K; ++k) {
        float4 xa = *(const float4*)&xT[k * 64 + rg * 4];
        float4 wb = *(const float4*)&Ws[k * 64 + c0];
        acc[0][0] = fmaf(xa.x, wb.x, acc[0][0]);
        acc[0][1] = fmaf(xa.x, wb.y, acc[0][1]);
        acc[0][2] = fmaf(xa.x, wb.z, acc[0][2]);
        acc[0][3] = fmaf(xa.x, wb.w, acc[0][3]);
        acc[1][0] = fmaf(xa.y, wb.x, acc[1][0]);
        acc[1][1] = fmaf(xa.y, wb.y, acc[1][1]);
        acc[1][2] = fmaf(xa.y, wb.z, acc[1][2]);
        acc[1][3] = fmaf(xa.y, wb.w, acc[1][3]);
        acc[2][0] = fmaf(xa.z, wb.x, acc[2][0]);
        acc[2][1] = fmaf(xa.z, wb.y, acc[2][1]);
        acc[2][2] = fmaf(xa.z, wb.z, acc[2][2]);
        acc[2][3] = fmaf(xa.z, wb.w, acc[2][3]);
        acc[3][0] = fmaf(xa.w, wb.x, acc[3][0]);
        acc[3][1] = fmaf(xa.w, wb.y, acc[3][1]);
        acc[3][2] = fmaf(xa.w, wb.z, acc[3][2]);
        acc[3][3] = fmaf(xa.w, wb.w, acc[3][3]);
    }

    // store h tile (float4 per row)
    #pragma unroll
    for (int i = 0; i < 4; ++i) {
        int row = r0 + rg * 4 + i;
        if (row < n) {
            float4 v = make_float4(acc[i][0], acc[i][1], acc[i][2], acc[i][3]);
            *(float4*)&h[(size_t)row * 64 + c0] = v;
        }
    }

    // alpha partial dots + cross-lane (over cg) + cross-wave reduce
    float a_s[4], a_d[4];
    #pragma unroll
    for (int j = 0; j < 4; ++j) { a_s[j] = a_src[c0 + j]; a_d[j] = a_dst[c0 + j]; }
    #pragma unroll
    for (int i = 0; i < 4; ++i) {
        float pa = acc[i][0] * a_s[0] + acc[i][1] * a_s[1] + acc[i][2] * a_s[2] + acc[i][3] * a_s[3];
        float pd = acc[i][0] * a_d[0] + acc[i][1] * a_d[1] + acc[i][2] * a_d[2] + acc[i][3] * a_d[3];
        pa += __shfl_xor(pa, 16); pa += __shfl_xor(pa, 32);
        pd += __shfl_xor(pd, 16); pd += __shfl_xor(pd, 32);
        if (cg == 0) { red_s[wv][rg * 4 + i] = pa; red_d[wv][rg * 4 + i] = pd; }
    }
    __syncthreads();
    if (t < 64) {
        int row = r0 + t;
        if (row < n) {
            as_[row] = red_s[0][t] + red_s[1][t] + red_s[2][t] + red_s[3][t];
            ad_[row] = red_d[0][t] + red_d[1][t] + red_d[2][t] + red_d[3][t];
        }
    }
}

// ---------------- per-dst aggregation (segment softmax + weighted sum) -----
// One wave per node; lane = output feature. Exact two-pass softmax.

template <bool RELU>
__global__ __launch_bounds__(256) void k_aggregate(
    const int* __restrict__ rowptr, const int* __restrict__ csrc,
    const float* __restrict__ h, const float* __restrict__ as_,
    const float* __restrict__ ad_, const float* __restrict__ bias,
    float* __restrict__ out, int n)
{
    const int lane = threadIdx.x & 63;
    const int node = blockIdx.x * 4 + (threadIdx.x >> 6);
    if (node >= n) return;

    const int start = rowptr[node];
    const int end   = rowptr[node + 1];
    const float adn = ad_[node];

    // pass 1: segment max
    float m = -1e30f;
    for (int base = start; base < end; base += 64) {
        int idx = base + lane;
        if (idx < end) {
            int s = csrc[idx];
            float e = as_[s] + adn;
            e = e > 0.f ? e : 0.2f * e;
            m = fmaxf(m, e);
        }
    }
    #pragma unroll
    for (int d = 32; d >= 1; d >>= 1) m = fmaxf(m, __shfl_xor(m, d));

    // pass 2: w = exp(e-m), accumulate w * h[src] (lane = feature)
    float acc = 0.f, dsum = 0.f;
    for (int base = start; base < end; base += 64) {
        int idx = base + lane;
        int s = 0; float w = 0.f;
        if (idx < end) {
            s = csrc[idx];
            float e = as_[s] + adn;
            e = e > 0.f ? e : 0.2f * e;
            w = __expf(e - m);
        }
        dsum += w;
        int cnt = min(64, end - base);
        for (int j = 0; j < cnt; ++j) {
            float wj = __shfl(w, j);
            int   sj = __shfl(s, j);
            acc = fmaf(wj, h[(size_t)sj * 64 + lane], acc);
        }
    }
    #pragma unroll
    for (int d = 32; d >= 1; d >>= 1) dsum += __shfl_xor(dsum, d);

    float o = acc / dsum + bias[lane];
    if (RELU) o = fmaxf(o, 0.f);
    out[(size_t)node * 64 + lane] = o;
}

// ---------------- launch ----------------

extern "C" void kernel_launch(void* const* d_in, const int* in_sizes, int n_in,
                              void* d_out, int out_size, void* d_ws, size_t ws_size,
                              hipStream_t stream) {
    const float* x   = (const float*)d_in[0];
    const int*   ei  = (const int*)  d_in[1];   // [2, E] row-major: src row 0, dst row 1
    const float* W1  = (const float*)d_in[2];
    const float* a1s = (const float*)d_in[3];
    const float* a1d = (const float*)d_in[4];
    const float* b1  = (const float*)d_in[5];
    const float* W2  = (const float*)d_in[6];
    const float* a2s = (const float*)d_in[7];
    const float* a2d = (const float*)d_in[8];
    const float* b2  = (const float*)d_in[9];
    float* out = (float*)d_out;

    const int N_ = NNODES, E_ = NEDGES, ET = NETOT;

    char* ws = (char*)d_ws;
    size_t off = 0;
    auto alloc = [&](size_t bytes) -> void* {
        void* p = ws + off;
        off += (bytes + 255) & ~(size_t)255;
        return p;
    };
    int*   deg    = (int*)alloc((size_t)N_ * 4);
    int*   rowptr = (int*)alloc((size_t)(N_ + 1) * 4);
    int*   cursor = (int*)alloc((size_t)N_ * 4);
    int*   bsum   = (int*)alloc(256 * 4);
    int*   boff   = (int*)alloc(256 * 4);
    int*   csrc   = (int*)alloc((size_t)ET * 4);
    float* h      = (float*)alloc((size_t)N_ * FOUT * 4);
    float* as_    = (float*)alloc((size_t)N_ * 4);
    float* ad_    = (float*)alloc((size_t)N_ * 4);
    float* xr2    = out;  // reuse d_out as layer-1 activation scratch

    const int NB = (N_ + 255) / 256;  // 196

    k_init_deg<<<NB, 256, 0, stream>>>(deg, N_);
    k_hist<<<(E_ + 255) / 256, 256, 0, stream>>>(ei + E_, deg, E_);
    k_scan1<<<NB, 256, 0, stream>>>(deg, bsum, N_);
    k_scan2<<<1, 256, 0, stream>>>(bsum, boff, NB);
    k_scan3<<<NB, 256, 0, stream>>>(deg, boff, rowptr, cursor, N_);
    k_fill<<<(ET + 255) / 256, 256, 0, stream>>>(ei, cursor, csrc, E_, N_);

    const int GB = (N_ + 63) / 64;    // 782 gemm blocks
    const int AB = (N_ + 3) / 4;      // 12500 aggregate blocks

    // layer 1
    gemm_alpha<128><<<GB, 256, 0, stream>>>(x, W1, a1s, a1d, h, as_, ad_, N_);
    k_aggregate<true><<<AB, 256, 0, stream>>>(rowptr, csrc, h, as_, ad_, b1, xr2, N_);
    // layer 2
    gemm_alpha<64><<<GB, 256, 0, stream>>>(xr2, W2, a2s, a2d, h, as_, ad_, N_);
    k_aggregate<false><<<AB, 256, 0, stream>>>(rowptr, csrc, h, as_, ad_, b2, out, N_);
}

// Round 2
// 295.137 us; speedup vs baseline: 1.1534x; 1.1534x over previous
//
#include <hip/hip_runtime.h>
#include <hip/hip_bf16.h>
#include <cstddef>

// ---------------------------------------------------------------------------
// GAT 2-layer forward. N=50000 nodes, E=800000 edges (+N self loops).
//   CSR build (deg hist -> scan -> fill)  [graph shared by both layers]
//   L1: gemm_alpha<128> -> aggregate<RELU=true>  (writes to d_out as scratch)
//   L2: gemm_alpha<64>  -> aggregate<RELU=false> (writes final d_out)
// R2: k_aggregate fast path (deg<=64): single register-resident gather,
//     v_readlane broadcast, 8-wide unrolled gather loop, 4 accumulators.
// ---------------------------------------------------------------------------

#define NNODES 50000
#define NEDGES 800000
#define NETOT  850000
#define FOUT   64

// ---------------- CSR build ----------------

__global__ void k_init_deg(int* __restrict__ deg, int n) {
    int i = blockIdx.x * 256 + threadIdx.x;
    if (i < n) deg[i] = 1;   // self loop
}

__global__ void k_hist(const int* __restrict__ dst, int* __restrict__ deg, int E) {
    int i = blockIdx.x * 256 + threadIdx.x;
    if (i < E) atomicAdd(&deg[dst[i]], 1);
}

__global__ void k_scan1(const int* __restrict__ deg, int* __restrict__ bsum, int n) {
    int t = threadIdx.x;
    int g = blockIdx.x * 256 + t;
    int v = (g < n) ? deg[g] : 0;
    #pragma unroll
    for (int d = 1; d < 64; d <<= 1) v += __shfl_xor(v, d);
    __shared__ int ws[4];
    if ((t & 63) == 0) ws[t >> 6] = v;
    __syncthreads();
    if (t == 0) bsum[blockIdx.x] = ws[0] + ws[1] + ws[2] + ws[3];
}

__global__ void k_scan2(const int* __restrict__ bsum, int* __restrict__ boff, int nb) {
    int t = threadIdx.x, lane = t & 63, wv = t >> 6;
    int v = (t < nb) ? bsum[t] : 0;
    int inc = v;
    #pragma unroll
    for (int d = 1; d < 64; d <<= 1) { int u = __shfl_up(inc, d); if (lane >= d) inc += u; }
    __shared__ int wsum[4];
    if (lane == 63) wsum[wv] = inc;
    __syncthreads();
    int woff = 0;
    for (int w = 0; w < wv; ++w) woff += wsum[w];
    if (t < nb) boff[t] = woff + inc - v;
}

__global__ void k_scan3(const int* __restrict__ deg, const int* __restrict__ boff,
                        int* __restrict__ rowptr, int* __restrict__ cursor, int n) {
    int t = threadIdx.x, lane = t & 63, wv = t >> 6;
    int g = blockIdx.x * 256 + t;
    int v = (g < n) ? deg[g] : 0;
    int inc = v;
    #pragma unroll
    for (int d = 1; d < 64; d <<= 1) { int u = __shfl_up(inc, d); if (lane >= d) inc += u; }
    __shared__ int wsum[4];
    if (lane == 63) wsum[wv] = inc;
    __syncthreads();
    int woff = 0;
    for (int w = 0; w < wv; ++w) woff += wsum[w];
    int excl = boff[blockIdx.x] + woff + (inc - v);
    if (g < n) {
        rowptr[g] = excl;
        cursor[g] = excl;
        if (g == n - 1) rowptr[n] = excl + v;
    }
}

__global__ void k_fill(const int* __restrict__ ei, int* __restrict__ cursor,
                       int* __restrict__ csrc, int E, int n) {
    int i = blockIdx.x * 256 + threadIdx.x;
    if (i < E) {
        int s = ei[i];
        int d = ei[E + i];
        int slot = atomicAdd(&cursor[d], 1);
        csrc[slot] = s;
    } else if (i < E + n) {
        int node = i - E;
        int slot = atomicAdd(&cursor[node], 1);
        csrc[slot] = node;
    }
}

// ---------------- GEMM + alpha (h = x@W, as = h@a_src, ad = h@a_dst) -------

template <int K>
__global__ __launch_bounds__(256) void gemm_alpha(
    const float* __restrict__ x, const float* __restrict__ W,
    const float* __restrict__ a_src, const float* __restrict__ a_dst,
    float* __restrict__ h, float* __restrict__ as_, float* __restrict__ ad_, int n)
{
    __shared__ __align__(16) float Ws[K * 64];   // Ws[k*64 + c]
    __shared__ __align__(16) float xT[K * 64];   // xT[k*64 + r]
    __shared__ float red_s[4][64];
    __shared__ float red_d[4][64];

    const int t = threadIdx.x;
    const int lane = t & 63;
    const int wv = t >> 6;
    const int rg = lane & 15;
    const int cg = lane >> 4;
    const int r0 = blockIdx.x * 64;
    const int c0 = wv * 16 + cg * 4;

    {
        const float4* Wg = (const float4*)W;
        float4* Wl = (float4*)Ws;
        for (int i = t; i < K * 16; i += 256) Wl[i] = Wg[i];
    }
    for (int i = t; i < 16 * K; i += 256) {
        int r = i & 63;
        int kq = i >> 6;
        int row = r0 + r;
        float4 v = make_float4(0.f, 0.f, 0.f, 0.f);
        if (row < n) v = ((const float4*)(x + (size_t)row * K))[kq];
        xT[(kq * 4 + 0) * 64 + r] = v.x;
        xT[(kq * 4 + 1) * 64 + r] = v.y;
        xT[(kq * 4 + 2) * 64 + r] = v.z;
        xT[(kq * 4 + 3) * 64 + r] = v.w;
    }
    __syncthreads();

    float acc[4][4];
    #pragma unroll
    for (int i = 0; i < 4; ++i)
        #pragma unroll
        for (int j = 0; j < 4; ++j) acc[i][j] = 0.f;

    #pragma unroll 4
    for (int k = 0; k < K; ++k) {
        float4 xa = *(const float4*)&xT[k * 64 + rg * 4];
        float4 wb = *(const float4*)&Ws[k * 64 + c0];
        acc[0][0] = fmaf(xa.x, wb.x, acc[0][0]);
        acc[0][1] = fmaf(xa.x, wb.y, acc[0][1]);
        acc[0][2] = fmaf(xa.x, wb.z, acc[0][2]);
        acc[0][3] = fmaf(xa.x, wb.w, acc[0][3]);
        acc[1][0] = fmaf(xa.y, wb.x, acc[1][0]);
        acc[1][1] = fmaf(xa.y, wb.y, acc[1][1]);
        acc[1][2] = fmaf(xa.y, wb.z, acc[1][2]);
        acc[1][3] = fmaf(xa.y, wb.w, acc[1][3]);
        acc[2][0] = fmaf(xa.z, wb.x, acc[2][0]);
        acc[2][1] = fmaf(xa.z, wb.y, acc[2][1]);
        acc[2][2] = fmaf(xa.z, wb.z, acc[2][2]);
        acc[2][3] = fmaf(xa.z, wb.w, acc[2][3]);
        acc[3][0] = fmaf(xa.w, wb.x, acc[3][0]);
        acc[3][1] = fmaf(xa.w, wb.y, acc[3][1]);
        acc[3][2] = fmaf(xa.w, wb.z, acc[3][2]);
        acc[3][3] = fmaf(xa.w, wb.w, acc[3][3]);
    }

    #pragma unroll
    for (int i = 0; i < 4; ++i) {
        int row = r0 + rg * 4 + i;
        if (row < n) {
            float4 v = make_float4(acc[i][0], acc[i][1], acc[i][2], acc[i][3]);
            *(float4*)&h[(size_t)row * 64 + c0] = v;
        }
    }

    float a_s[4], a_d[4];
    #pragma unroll
    for (int j = 0; j < 4; ++j) { a_s[j] = a_src[c0 + j]; a_d[j] = a_dst[c0 + j]; }
    #pragma unroll
    for (int i = 0; i < 4; ++i) {
        float pa = acc[i][0] * a_s[0] + acc[i][1] * a_s[1] + acc[i][2] * a_s[2] + acc[i][3] * a_s[3];
        float pd = acc[i][0] * a_d[0] + acc[i][1] * a_d[1] + acc[i][2] * a_d[2] + acc[i][3] * a_d[3];
        pa += __shfl_xor(pa, 16); pa += __shfl_xor(pa, 32);
        pd += __shfl_xor(pd, 16); pd += __shfl_xor(pd, 32);
        if (cg == 0) { red_s[wv][rg * 4 + i] = pa; red_d[wv][rg * 4 + i] = pd; }
    }
    __syncthreads();
    if (t < 64) {
        int row = r0 + t;
        if (row < n) {
            as_[row] = red_s[0][t] + red_s[1][t] + red_s[2][t] + red_s[3][t];
            ad_[row] = red_d[0][t] + red_d[1][t] + red_d[2][t] + red_d[3][t];
        }
    }
}

// ---------------- per-dst aggregation (segment softmax + weighted sum) -----
// One wave per node; lane = output feature.
// Fast path (deg<=64, always hit for this graph): gather (s,e) once into
// registers, wave-reduce max & denom, then 8-wide unrolled readlane-broadcast
// gather of h rows with 4 independent accumulators (8 outstanding loads).

#define RL(v, j) __builtin_amdgcn_readlane((v), (j))

template <bool RELU>
__global__ __launch_bounds__(256) void k_aggregate(
    const int* __restrict__ rowptr, const int* __restrict__ csrc,
    const float* __restrict__ h, const float* __restrict__ as_,
    const float* __restrict__ ad_, const float* __restrict__ bias,
    float* __restrict__ out, int n)
{
    const int lane = threadIdx.x & 63;
    const int node = blockIdx.x * 4 + (threadIdx.x >> 6);
    if (node >= n) return;

    const int start = rowptr[node];
    const int end   = rowptr[node + 1];
    const int deg   = end - start;
    const float adn = ad_[node];
    const float* __restrict__ hp = h + lane;   // lane-fixed feature column

    float acc0 = 0.f, acc1 = 0.f, acc2 = 0.f, acc3 = 0.f;
    float dsum;

    if (deg <= 64) {
        // ---- single-pass fast path ----
        int s = 0;
        float e = -1e30f;
        if (lane < deg) {
            s = csrc[start + lane];
            float t = as_[s] + adn;
            e = t > 0.f ? t : 0.2f * t;
        }
        float m = e;
        #pragma unroll
        for (int d = 32; d >= 1; d >>= 1) m = fmaxf(m, __shfl_xor(m, d));

        float w = (lane < deg) ? __expf(e - m) : 0.f;  // inactive lanes: w=0, s=0
        dsum = w;
        #pragma unroll
        for (int d = 32; d >= 1; d >>= 1) dsum += __shfl_xor(dsum, d);

        int off = s << 6;                 // element offset of row s
        int wu = __float_as_uint(w);
        int cnt = (deg + 7) & ~7;         // round up; padded lanes have w=0
        for (int j = 0; j < cnt; j += 8) {
            int   o0 = RL(off, j + 0), o1 = RL(off, j + 1);
            int   o2 = RL(off, j + 2), o3 = RL(off, j + 3);
            int   o4 = RL(off, j + 4), o5 = RL(off, j + 5);
            int   o6 = RL(off, j + 6), o7 = RL(off, j + 7);
            float w0 = __uint_as_float(RL(wu, j + 0));
            float w1 = __uint_as_float(RL(wu, j + 1));
            float w2 = __uint_as_float(RL(wu, j + 2));
            float w3 = __uint_as_float(RL(wu, j + 3));
            float w4 = __uint_as_float(RL(wu, j + 4));
            float w5 = __uint_as_float(RL(wu, j + 5));
            float w6 = __uint_as_float(RL(wu, j + 6));
            float w7 = __uint_as_float(RL(wu, j + 7));
            float v0 = hp[o0], v1 = hp[o1], v2 = hp[o2], v3 = hp[o3];
            float v4 = hp[o4], v5 = hp[o5], v6 = hp[o6], v7 = hp[o7];
            acc0 = fmaf(w0, v0, acc0);
            acc1 = fmaf(w1, v1, acc1);
            acc2 = fmaf(w2, v2, acc2);
            acc3 = fmaf(w3, v3, acc3);
            acc0 = fmaf(w4, v4, acc0);
            acc1 = fmaf(w5, v5, acc1);
            acc2 = fmaf(w6, v6, acc2);
            acc3 = fmaf(w7, v7, acc3);
        }
    } else {
        // ---- general chunked two-pass path (rare) ----
        float m = -1e30f;
        for (int base = start; base < end; base += 64) {
            int idx = base + lane;
            if (idx < end) {
                int s = csrc[idx];
                float e = as_[s] + adn;
                e = e > 0.f ? e : 0.2f * e;
                m = fmaxf(m, e);
            }
        }
        #pragma unroll
        for (int d = 32; d >= 1; d >>= 1) m = fmaxf(m, __shfl_xor(m, d));

        dsum = 0.f;
        for (int base = start; base < end; base += 64) {
            int idx = base + lane;
            int s = 0; float w = 0.f;
            if (idx < end) {
                s = csrc[idx];
                float e = as_[s] + adn;
                e = e > 0.f ? e : 0.2f * e;
                w = __expf(e - m);
            }
            dsum += w;
            int off = s << 6;
            int wu = __float_as_uint(w);
            int cnt = min(64, end - base);
            int cr = (cnt + 3) & ~3;
            for (int j = 0; j < cr; j += 4) {
                int   o0 = RL(off, j + 0), o1 = RL(off, j + 1);
                int   o2 = RL(off, j + 2), o3 = RL(off, j + 3);
                float w0 = __uint_as_float(RL(wu, j + 0));
                float w1 = __uint_as_float(RL(wu, j + 1));
                float w2 = __uint_as_float(RL(wu, j + 2));
                float w3 = __uint_as_float(RL(wu, j + 3));
                float v0 = hp[o0], v1 = hp[o1], v2 = hp[o2], v3 = hp[o3];
                acc0 = fmaf(w0, v0, acc0);
                acc1 = fmaf(w1, v1, acc1);
                acc2 = fmaf(w2, v2, acc2);
                acc3 = fmaf(w3, v3, acc3);
            }
        }
        #pragma unroll
        for (int d = 32; d >= 1; d >>= 1) dsum += __shfl_xor(dsum, d);
    }

    float acc = (acc0 + acc1) + (acc2 + acc3);
    float o = acc / dsum + bias[lane];
    if (RELU) o = fmaxf(o, 0.f);
    out[(size_t)node * 64 + lane] = o;
}

// ---------------- launch ----------------

extern "C" void kernel_launch(void* const* d_in, const int* in_sizes, int n_in,
                              void* d_out, int out_size, void* d_ws, size_t ws_size,
                              hipStream_t stream) {
    const float* x   = (const float*)d_in[0];
    const int*   ei  = (const int*)  d_in[1];   // [2, E] row-major: src row 0, dst row 1
    const float* W1  = (const float*)d_in[2];
    const float* a1s = (const float*)d_in[3];
    const float* a1d = (const float*)d_in[4];
    const float* b1  = (const float*)d_in[5];
    const float* W2  = (const float*)d_in[6];
    const float* a2s = (const float*)d_in[7];
    const float* a2d = (const float*)d_in[8];
    const float* b2  = (const float*)d_in[9];
    float* out = (float*)d_out;

    const int N_ = NNODES, E_ = NEDGES, ET = NETOT;

    char* ws = (char*)d_ws;
    size_t off = 0;
    auto alloc = [&](size_t bytes) -> void* {
        void* p = ws + off;
        off += (bytes + 255) & ~(size_t)255;
        return p;
    };
    int*   deg    = (int*)alloc((size_t)N_ * 4);
    int*   rowptr = (int*)alloc((size_t)(N_ + 1) * 4);
    int*   cursor = (int*)alloc((size_t)N_ * 4);
    int*   bsum   = (int*)alloc(256 * 4);
    int*   boff   = (int*)alloc(256 * 4);
    int*   csrc   = (int*)alloc((size_t)ET * 4);
    float* h      = (float*)alloc((size_t)N_ * FOUT * 4);
    float* as_    = (float*)alloc((size_t)N_ * 4);
    float* ad_    = (float*)alloc((size_t)N_ * 4);
    float* xr2    = out;  // reuse d_out as layer-1 activation scratch

    const int NB = (N_ + 255) / 256;  // 196

    k_init_deg<<<NB, 256, 0, stream>>>(deg, N_);
    k_hist<<<(E_ + 255) / 256, 256, 0, stream>>>(ei + E_, deg, E_);
    k_scan1<<<NB, 256, 0, stream>>>(deg, bsum, N_);
    k_scan2<<<1, 256, 0, stream>>>(bsum, boff, NB);
    k_scan3<<<NB, 256, 0, stream>>>(deg, boff, rowptr, cursor, N_);
    k_fill<<<(ET + 255) / 256, 256, 0, stream>>>(ei, cursor, csrc, E_, N_);

    const int GB = (N_ + 63) / 64;    // 782 gemm blocks
    const int AB = (N_ + 3) / 4;      // 12500 aggregate blocks

    // layer 1
    gemm_alpha<128><<<GB, 256, 0, stream>>>(x, W1, a1s, a1d, h, as_, ad_, N_);
    k_aggregate<true><<<AB, 256, 0, stream>>>(rowptr, csrc, h, as_, ad_, b1, xr2, N_);
    // layer 2
    gemm_alpha<64><<<GB, 256, 0, stream>>>(xr2, W2, a2s, a2d, h, as_, ad_, N_);
    k_aggregate<false><<<AB, 256, 0, stream>>>(rowptr, csrc, h, as_, ad_, b2, out, N_);
}